// Round 1
// baseline (633.199 us; speedup 1.0000x reference)
//
#include <hip/hip_runtime.h>
#include <math.h>

// ---- problem constants ----
#define NLATC   361
#define NLONC   722
#define MMAXC   362
#define LMAXC   361
#define NLK     16      // N_LATENT
#define TSTEPS  8
#define LCUT    128     // truncation: sigma_n[l>=128] < 1e-13 -> negligible
#define MCUT    128     // m <= l <= 127
#define PHI_F   0.8824969025845955f   // exp(-6/48)
#define FOURPI  12.566370614359172f

// ============================================================
// K0: trig basis  Bm[mc][j] (row stride 724 for 16B alignment)
//   c=0: w*4pi*cos(2*pi*m*j/722),  c=1: -w*4pi*sin(...)
//   w = 1 for m==0 else 2.  (imag-DC column is sin(0)=0 -> auto-correct)
// ============================================================
__global__ __launch_bounds__(256) void k_basis(float* __restrict__ Bm) {
    int idx = blockIdx.x * 256 + threadIdx.x;
    if (idx >= 2 * MCUT * NLONC) return;
    int j  = idx % NLONC;
    int mc = idx / NLONC;
    int m = mc >> 1, c = mc & 1;
    int r = (m * j) % NLONC;                   // exact integer phase reduction
    float th = (float)r * (6.283185307179586f / 722.0f);
    float s, co;
    sincosf(th, &s, &co);
    float w = (m == 0 ? 1.0f : 2.0f) * FOURPI;
    Bm[(size_t)mc * 724 + j] = c ? (-w * s) : (w * co);
}

// ============================================================
// K1: AR(1) scan.  Emits coeff BEFORE update.
//   cA[t][n][l][m][c], compact rectangle l<128, m<128 (zeros for m>l flow
//   through naturally since coeff0 and sigma_n are triangular).
//   thread = (n, l, m), m fastest -> coalesced reads of coeff0/sigma/xi
//   and coalesced writes.
// ============================================================
__global__ __launch_bounds__(256) void k_scan(const float* __restrict__ coeff0,
                                              const float* __restrict__ sigma_n,
                                              const float* __restrict__ xi,
                                              float* __restrict__ cA) {
    int tid = blockIdx.x * 256 + threadIdx.x;   // 16*128*128 = 262144 threads
    int m = tid & 127;
    int l = (tid >> 7) & 127;
    int n = tid >> 14;
    float sg = sigma_n[(size_t)l * MMAXC + m];
    const float* c0p = coeff0 + (((size_t)n * LMAXC + l) * MMAXC + m) * 2;
    float cr = c0p[0], ci = c0p[1];
#pragma unroll
    for (int t = 0; t < TSTEPS; ++t) {
        size_t o = ((((size_t)t * NLK + n) * LCUT + l) * MCUT + m) * 2;
        cA[o]     = cr;
        cA[o + 1] = ci;
        if (t < TSTEPS - 1) {
            const float* xp = xi + ((((size_t)t * NLK + n) * LMAXC + l) * MMAXC + m) * 2;
            cr = PHI_F * cr + sg * xp[0];
            ci = PHI_F * ci + sg * xp[1];
        }
    }
}

// ============================================================
// K1b: transpose pct[m][l][k] -> pT[l][k][m]  (m,l < 128 slice)
//   so K2's per-(m) lane reads are coalesced over m.
// ============================================================
__global__ __launch_bounds__(256) void k_transpose(const float* __restrict__ pct,
                                                   float* __restrict__ pT) {
    __shared__ float sm[32][33];
    int k0 = blockIdx.x * 32;      // 12 tiles cover 361
    int m0 = blockIdx.y * 32;      // 4 tiles cover 128
    int l  = blockIdx.z;           // 128
    int tx = threadIdx.x & 31, ty = threadIdx.x >> 5;   // 32 x 8
#pragma unroll
    for (int i = 0; i < 4; ++i) {
        int m = m0 + ty + 8 * i;
        int k = k0 + tx;
        sm[ty + 8 * i][tx] = (k < NLATC)
            ? pct[((size_t)m * LMAXC + l) * NLATC + k] : 0.0f;
    }
    __syncthreads();
#pragma unroll
    for (int i = 0; i < 4; ++i) {
        int k = k0 + ty + 8 * i;
        if (k < NLATC)
            pT[((size_t)l * NLATC + k) * MCUT + m0 + tx] = sm[tx][ty + 8 * i];
    }
}

// ============================================================
// K2: Legendre contraction  xs[t][n][k][m][c] = sum_l cA[t][n][l][m][c]*pT[l][k][m]
//   block = (k-tile of 8) x (tn-group of 8);  thread = (m,c) pair (tid = 2m+c)
//   -> cA reads are 256-consecutive-float rows (perfectly coalesced),
//      pT reads coalesced over m (c-pairs merge).
//   Wave-uniform l start = wave's min m (coeff zero for l<m anyway).
// ============================================================
__global__ __launch_bounds__(256) void k_legendre(const float* __restrict__ cA,
                                                  const float* __restrict__ pT,
                                                  float* __restrict__ xs) {
    int tid = threadIdx.x;
    int k0  = blockIdx.x * 8;     // 46 tiles cover 361
    int tn0 = blockIdx.y * 8;     // 16 groups cover 128
    int lstart = (tid >> 6) * 32; // wave-uniform
    float acc[8][8];
#pragma unroll
    for (int kk = 0; kk < 8; ++kk)
#pragma unroll
        for (int r = 0; r < 8; ++r) acc[kk][r] = 0.0f;

    for (int l = lstart; l < LCUT; ++l) {
        float a[8];
        const float* ap = cA + ((size_t)tn0 * LCUT + l) * (MCUT * 2) + tid;
#pragma unroll
        for (int r = 0; r < 8; ++r) a[r] = ap[(size_t)r * LCUT * MCUT * 2];
        float p[8];
        const float* pp = pT + ((size_t)l * NLATC + k0) * MCUT + (tid >> 1);
#pragma unroll
        for (int kk = 0; kk < 8; ++kk)
            p[kk] = (k0 + kk < NLATC) ? pp[(size_t)kk * MCUT] : 0.0f;
#pragma unroll
        for (int kk = 0; kk < 8; ++kk)
#pragma unroll
            for (int r = 0; r < 8; ++r) acc[kk][r] += a[r] * p[kk];
    }
#pragma unroll
    for (int kk = 0; kk < 8; ++kk) {
        if (k0 + kk >= NLATC) continue;
#pragma unroll
        for (int r = 0; r < 8; ++r)
            xs[((size_t)(tn0 + r) * NLATC + k0 + kk) * (MCUT * 2) + tid] = acc[kk][r];
    }
}

// ============================================================
// K3: DFT as fp32 GEMM.  C(46208 x 722) = A(46208 x 256) * B(256 x 722)
//   128x128 block tile, 256 threads, 8x8 micro-tile, BK=16.
// ============================================================
__global__ __launch_bounds__(256) void k_gemm(const float* __restrict__ A,
                                              const float* __restrict__ Bm,
                                              float* __restrict__ C) {
    __shared__ float As[16][132];   // [k][row], +4 pad
    __shared__ float Bs[16][132];   // [k][col], +4 pad
    int tid = threadIdx.x;
    int tx = tid & 15, ty = tid >> 4;
    int row0 = blockIdx.x * 128;    // 361 tiles, exact
    int j0   = blockIdx.y * 128;    // 6 tiles, last partial (722)
    float acc[8][8];
#pragma unroll
    for (int r = 0; r < 8; ++r)
#pragma unroll
        for (int c = 0; c < 8; ++c) acc[r][c] = 0.0f;

    for (int k0 = 0; k0 < 256; k0 += 16) {
        // A tile: 128 rows x 16 k, transposed into LDS
#pragma unroll
        for (int i = 0; i < 2; ++i) {
            int r  = (tid >> 2) + i * 64;
            int kk = (tid & 3) * 4;
            float4 v = *(const float4*)(A + (size_t)(row0 + r) * 256 + k0 + kk);
            As[kk + 0][r] = v.x; As[kk + 1][r] = v.y;
            As[kk + 2][r] = v.z; As[kk + 3][r] = v.w;
        }
        // B tile: 16 k x 128 j (guarded on j)
#pragma unroll
        for (int i = 0; i < 2; ++i) {
            int kk = (tid >> 5) + i * 8;
            int c4 = (tid & 31) * 4;
            int j  = j0 + c4;
            float4 v;
            if (j + 3 < NLONC) {
                v = *(const float4*)(Bm + (size_t)(k0 + kk) * 724 + j);
            } else {
                v.x = (j + 0 < NLONC) ? Bm[(size_t)(k0 + kk) * 724 + j + 0] : 0.0f;
                v.y = (j + 1 < NLONC) ? Bm[(size_t)(k0 + kk) * 724 + j + 1] : 0.0f;
                v.z = (j + 2 < NLONC) ? Bm[(size_t)(k0 + kk) * 724 + j + 2] : 0.0f;
                v.w = (j + 3 < NLONC) ? Bm[(size_t)(k0 + kk) * 724 + j + 3] : 0.0f;
            }
            *(float4*)&Bs[kk][c4] = v;
        }
        __syncthreads();
#pragma unroll
        for (int kk = 0; kk < 16; ++kk) {
            float4 a0 = *(const float4*)&As[kk][ty * 8];
            float4 a1 = *(const float4*)&As[kk][ty * 8 + 4];
            float4 b0 = *(const float4*)&Bs[kk][tx * 8];
            float4 b1 = *(const float4*)&Bs[kk][tx * 8 + 4];
            float a[8] = {a0.x, a0.y, a0.z, a0.w, a1.x, a1.y, a1.z, a1.w};
            float b[8] = {b0.x, b0.y, b0.z, b0.w, b1.x, b1.y, b1.z, b1.w};
#pragma unroll
            for (int r = 0; r < 8; ++r)
#pragma unroll
                for (int c = 0; c < 8; ++c) acc[r][c] += a[r] * b[c];
        }
        __syncthreads();
    }
    // store (float2: 722-stride rows are only 8B-aligned for odd rows)
#pragma unroll
    for (int r = 0; r < 8; ++r) {
        size_t row = row0 + ty * 8 + r;
        float* cp = C + row * NLONC + j0 + tx * 8;
#pragma unroll
        for (int c = 0; c < 8; c += 2) {
            int j = j0 + tx * 8 + c;
            if (j < NLONC) {   // j even, so j+1 <= 721 whenever j < 722
                float2 v; v.x = acc[r][c]; v.y = acc[r][c + 1];
                *(float2*)(cp + c) = v;
            }
        }
    }
}

extern "C" void kernel_launch(void* const* d_in, const int* in_sizes, int n_in,
                              void* d_out, int out_size, void* d_ws, size_t ws_size,
                              hipStream_t stream) {
    (void)in_sizes; (void)n_in; (void)out_size; (void)ws_size;
    const float* sigma_n = (const float*)d_in[1];
    const float* coeff0  = (const float*)d_in[2];
    const float* xi      = (const float*)d_in[3];
    const float* pct     = (const float*)d_in[4];
    float* out = (float*)d_out;

    char* ws = (char*)d_ws;
    float* cA = (float*)ws;                                   // 16.8 MB
    size_t off = (size_t)TSTEPS * NLK * LCUT * MCUT * 2 * 4;
    float* pT = (float*)(ws + off);                           // 23.7 MB
    off += (size_t)LCUT * NLATC * MCUT * 4;
    float* xs = (float*)(ws + off);                           // 47.3 MB
    off += (size_t)TSTEPS * NLK * NLATC * MCUT * 2 * 4;
    float* Bm = (float*)(ws + off);                           // 0.74 MB
    off += (size_t)2 * MCUT * 724 * 4;

    k_basis<<<(2 * MCUT * NLONC + 255) / 256, 256, 0, stream>>>(Bm);
    k_scan<<<(NLK * LCUT * MCUT) / 256, 256, 0, stream>>>(coeff0, sigma_n, xi, cA);
    k_transpose<<<dim3(12, 4, LCUT), 256, 0, stream>>>(pct, pT);
    k_legendre<<<dim3(46, 16), 256, 0, stream>>>(cA, pT, xs);
    k_gemm<<<dim3(361, 6), 256, 0, stream>>>(xs, Bm, out);
}

// Round 2
// 421.616 us; speedup vs baseline: 1.5018x; 1.5018x over previous
//
#include <hip/hip_runtime.h>
#include <math.h>

// ---- problem constants ----
#define NLATC   361
#define NLONC   722
#define MMAXC   362
#define LMAXC   361
#define NLK     16
#define TSTEPS  8
#define LCUT    128    // sigma_n[l>=128] < 1e-11 -> negligible
#define MCUT    128
#define MCK     256    // 2*MCUT: DFT K-dim
#define TNK     46208  // 8*16*361 rows of the DFT GEMM
#define NPAD    768    // 722 padded to 6*128
#define KPAD    384    // 361 padded to 6*64
#define PHI_F   0.8824969025845955f
#define FOURPI  12.566370614359172f
#define ASCALE  1024.0f      // 2^10: lift coeffs away from fp16 denormals
#define OSCALE  0.0009765625f // 2^-10

typedef _Float16 half8 __attribute__((ext_vector_type(8)));
typedef float floatx4 __attribute__((ext_vector_type(4)));

// ============================================================
// K0: trig basis, fp16, layout Bf[j][mc]  (j<768, zero-padded)
//   mc=2m+c: c=0 -> w*4pi*cos(2pi m j/722), c=1 -> -w*4pi*sin(...)
// ============================================================
__global__ __launch_bounds__(256) void k_basis2(_Float16* __restrict__ Bf) {
    int idx = blockIdx.x * 256 + threadIdx.x;      // 768*256 threads
    int j = idx >> 8, mc = idx & 255;
    int m = mc >> 1, c = mc & 1;
    float v = 0.0f;
    if (j < NLONC) {
        int r = (m * j) % NLONC;
        float th = (float)r * (6.283185307179586f / 722.0f);
        float s, co;
        sincosf(th, &s, &co);
        float wq = (m == 0 ? 1.0f : 2.0f) * FOURPI;
        v = c ? (-wq * s) : (wq * co);
    }
    Bf[idx] = (_Float16)v;
}

// ============================================================
// K1: AR(1) scan (fp32, coalesced everything). cA[(t*16+n)*128+l][256] with
//   fastest dim mc=2m+c.  (unchanged from R1)
// ============================================================
__global__ __launch_bounds__(256) void k_scan(const float* __restrict__ coeff0,
                                              const float* __restrict__ sigma_n,
                                              const float* __restrict__ xi,
                                              float* __restrict__ cA) {
    int tid = blockIdx.x * 256 + threadIdx.x;   // 16*128*128
    int m = tid & 127;
    int l = (tid >> 7) & 127;
    int n = tid >> 14;
    float sg = sigma_n[(size_t)l * MMAXC + m];
    const float* c0p = coeff0 + (((size_t)n * LMAXC + l) * MMAXC + m) * 2;
    float cr = c0p[0], ci = c0p[1];
#pragma unroll
    for (int t = 0; t < TSTEPS; ++t) {
        size_t o = ((((size_t)t * NLK + n) * LCUT + l) * MCUT + m) * 2;
        cA[o] = cr; cA[o + 1] = ci;
        if (t < TSTEPS - 1) {
            const float* xp = xi + ((((size_t)t * NLK + n) * LMAXC + l) * MMAXC + m) * 2;
            cr = PHI_F * cr + sg * xp[0];
            ci = PHI_F * ci + sg * xp[1];
        }
    }
}

// ============================================================
// K1b: cA fp32 [(tn)l][mc] -> cB fp16 [m][r=(c*128+tn)][l]  (scaled by 2^10)
//   64x64 LDS tile transpose; both global sides coalesced.
// ============================================================
__global__ __launch_bounds__(256) void k_castA(const float* __restrict__ cA,
                                               _Float16* __restrict__ cB) {
    __shared__ _Float16 sm[64][66];
    int tx = threadIdx.x & 63, ty = threadIdx.x >> 6;
    int tnl0 = blockIdx.x * 64;        // 256 tiles over tn*128+l
    int mc0  = blockIdx.y * 64;        // 4 tiles over mc
    int tn = tnl0 >> 7, l0 = tnl0 & 127;
#pragma unroll
    for (int i = 0; i < 16; ++i) {
        int row = ty * 16 + i;         // l_local
        sm[row][tx] = (_Float16)(cA[(size_t)(tnl0 + row) * MCK + mc0 + tx] * ASCALE);
    }
    __syncthreads();
#pragma unroll
    for (int i = 0; i < 16; ++i) {
        int rm = ty * 16 + i;          // mc_local
        int mc = mc0 + rm, m = mc >> 1, c = mc & 1;
        cB[((size_t)m * 256 + c * 128 + tn) * 128 + l0 + tx] = sm[tx][rm];
    }
}

// ============================================================
// K1c: pct[m][l][k] fp32 -> pTf fp16 [m][k(384-pad)][l]  (m,l<128)
// ============================================================
__global__ __launch_bounds__(256) void k_transP(const float* __restrict__ pct,
                                                _Float16* __restrict__ pTf) {
    __shared__ _Float16 sm[64][66];
    int tx = threadIdx.x & 63, ty = threadIdx.x >> 6;
    int k0 = blockIdx.x * 64;          // 6
    int l0 = blockIdx.y * 64;          // 2
    int m  = blockIdx.z;               // 128
#pragma unroll
    for (int i = 0; i < 16; ++i) {
        int row = ty * 16 + i;         // l_local
        int k = k0 + tx;
        sm[row][tx] = (k < NLATC)
            ? (_Float16)pct[((size_t)m * LMAXC + l0 + row) * NLATC + k] : (_Float16)0.0f;
    }
    __syncthreads();
#pragma unroll
    for (int i = 0; i < 16; ++i) {
        int kr = ty * 16 + i;          // k_local
        pTf[((size_t)m * KPAD + k0 + kr) * 128 + l0 + tx] = sm[tx][kr];
    }
}

// ============================================================
// K2: Legendre via MFMA, batched over m.
//   C_m[r=(c,t,n); 256][k; 64-tile] = sum_l cB[m][r][l] * pTf[m][k][l]
//   K-loop over l starts at m&~31 (coeff triangular-zero below m).
//   Store fp16 -> xsTh[mc][tn*361+k].
// ============================================================
__global__ __launch_bounds__(256) void k_leg(const _Float16* __restrict__ cB,
                                             const _Float16* __restrict__ pTf,
                                             _Float16* __restrict__ xsTh) {
    __shared__ _Float16 As[256][40];   // [r][l], pad 40 (2-way = free)
    __shared__ _Float16 Bs[64][40];    // [k][l]
    int tid = threadIdx.x;
    int k0c = blockIdx.x * 64;         // 6 tiles cover 384
    int m   = blockIdx.y;              // 128
    int w = tid >> 6, lane = tid & 63, m16 = lane & 15, quad = lane >> 4;
    floatx4 acc[4][4];
#pragma unroll
    for (int i = 0; i < 4; ++i)
#pragma unroll
        for (int j = 0; j < 4; ++j) acc[i][j] = (floatx4)(0.0f);

    int lt0 = m & ~31;
    for (int lt = lt0; lt < 128; lt += 32) {
#pragma unroll
        for (int it = 0; it < 4; ++it) {
            int r = (tid >> 2) + 64 * it, lc = (tid & 3) * 8;
            *(half8*)&As[r][lc] = *(const half8*)&cB[((size_t)m * 256 + r) * 128 + lt + lc];
        }
        {
            int k = tid >> 2, lc = (tid & 3) * 8;
            *(half8*)&Bs[k][lc] = *(const half8*)&pTf[((size_t)m * KPAD + k0c + k) * 128 + lt + lc];
        }
        __syncthreads();
        half8 a[4], b[4];
#pragma unroll
        for (int i = 0; i < 4; ++i) a[i] = *(const half8*)&As[w * 64 + i * 16 + m16][quad * 8];
#pragma unroll
        for (int j = 0; j < 4; ++j) b[j] = *(const half8*)&Bs[j * 16 + m16][quad * 8];
#pragma unroll
        for (int i = 0; i < 4; ++i)
#pragma unroll
            for (int j = 0; j < 4; ++j)
                acc[i][j] = __builtin_amdgcn_mfma_f32_16x16x32_f16(a[i], b[j], acc[i][j], 0, 0, 0);
        __syncthreads();
    }
#pragma unroll
    for (int i = 0; i < 4; ++i)
#pragma unroll
        for (int j = 0; j < 4; ++j)
#pragma unroll
            for (int reg = 0; reg < 4; ++reg) {
                int r = w * 64 + i * 16 + quad * 4 + reg;
                int c = r >> 7, tn = r & 127;
                int k = k0c + j * 16 + m16;
                if (k < NLATC)
                    xsTh[(size_t)(2 * m + c) * TNK + tn * NLATC + k] = (_Float16)acc[i][j][reg];
            }
}

// ============================================================
// K2b: xsTh fp16 [mc][tnk] -> xsA fp16 [tnk][mc] (64x64 tile transpose)
// ============================================================
__global__ __launch_bounds__(256) void k_castXs(const _Float16* __restrict__ xsTh,
                                                _Float16* __restrict__ xsA) {
    __shared__ _Float16 sm[64][66];
    int tx = threadIdx.x & 63, ty = threadIdx.x >> 6;
    int t0  = blockIdx.x * 64;         // 722 tiles over tnk
    int mc0 = blockIdx.y * 64;         // 4 tiles over mc
#pragma unroll
    for (int i = 0; i < 16; ++i) {
        int row = ty * 16 + i;         // mc_local
        sm[row][tx] = xsTh[(size_t)(mc0 + row) * TNK + t0 + tx];
    }
    __syncthreads();
#pragma unroll
    for (int i = 0; i < 16; ++i) {
        int row = ty * 16 + i;         // tnk_local
        xsA[(size_t)(t0 + row) * MCK + mc0 + tx] = sm[tx][row];
    }
}

// ============================================================
// K3: DFT via MFMA.  C(46208x722) = xsA(46208x256) * Bf^T ; Bf is [j][mc].
//   128x128 tile, 2x2 waves, 4x4 MFMA tiles each, BK=32, K=256.
//   Output scaled by 2^-10 to undo ASCALE.
// ============================================================
__global__ __launch_bounds__(256) void k_gemm2(const _Float16* __restrict__ A,
                                               const _Float16* __restrict__ Bf,
                                               float* __restrict__ C) {
    __shared__ _Float16 As[128][40];
    __shared__ _Float16 Bs[128][40];
    int tid = threadIdx.x;
    int row0 = blockIdx.x * 128;       // 361 exact
    int j0   = blockIdx.y * 128;       // 6 tiles (768 pad)
    int w = tid >> 6, lane = tid & 63, m16 = lane & 15, quad = lane >> 4;
    int wr = (w & 1) * 64, wc = (w >> 1) * 64;
    floatx4 acc[4][4];
#pragma unroll
    for (int i = 0; i < 4; ++i)
#pragma unroll
        for (int j = 0; j < 4; ++j) acc[i][j] = (floatx4)(0.0f);

    for (int k0 = 0; k0 < MCK; k0 += 32) {
#pragma unroll
        for (int it = 0; it < 2; ++it) {
            int r = (tid >> 2) + 64 * it, kc = (tid & 3) * 8;
            *(half8*)&As[r][kc] = *(const half8*)&A[(size_t)(row0 + r) * MCK + k0 + kc];
            *(half8*)&Bs[r][kc] = *(const half8*)&Bf[(size_t)(j0 + r) * MCK + k0 + kc];
        }
        __syncthreads();
        half8 a[4], b[4];
#pragma unroll
        for (int i = 0; i < 4; ++i) a[i] = *(const half8*)&As[wr + i * 16 + m16][quad * 8];
#pragma unroll
        for (int j = 0; j < 4; ++j) b[j] = *(const half8*)&Bs[wc + j * 16 + m16][quad * 8];
#pragma unroll
        for (int i = 0; i < 4; ++i)
#pragma unroll
            for (int j = 0; j < 4; ++j)
                acc[i][j] = __builtin_amdgcn_mfma_f32_16x16x32_f16(a[i], b[j], acc[i][j], 0, 0, 0);
        __syncthreads();
    }
#pragma unroll
    for (int i = 0; i < 4; ++i)
#pragma unroll
        for (int j = 0; j < 4; ++j)
#pragma unroll
            for (int reg = 0; reg < 4; ++reg) {
                int row = row0 + wr + i * 16 + quad * 4 + reg;
                int col = j0 + wc + j * 16 + m16;
                if (col < NLONC)
                    C[(size_t)row * NLONC + col] = acc[i][j][reg] * OSCALE;
            }
}

extern "C" void kernel_launch(void* const* d_in, const int* in_sizes, int n_in,
                              void* d_out, int out_size, void* d_ws, size_t ws_size,
                              hipStream_t stream) {
    (void)in_sizes; (void)n_in; (void)out_size; (void)ws_size;
    const float* sigma_n = (const float*)d_in[1];
    const float* coeff0  = (const float*)d_in[2];
    const float* xi      = (const float*)d_in[3];
    const float* pct     = (const float*)d_in[4];
    float* out = (float*)d_out;

    char* ws = (char*)d_ws;
    size_t off = 0;
    float*    cA   = (float*)(ws + off);    off += (size_t)128 * 128 * MCK * 4;        // 16.78 MB
    _Float16* cB   = (_Float16*)(ws + off); off += (size_t)128 * 256 * 128 * 2;        //  8.39 MB
    _Float16* pTf  = (_Float16*)(ws + off); off += (size_t)128 * KPAD * 128 * 2;       // 12.58 MB
    _Float16* xsTh = (_Float16*)(ws + off); off += (size_t)MCK * TNK * 2;              // 23.66 MB
    _Float16* xsA  = (_Float16*)(ws + off); off += (size_t)TNK * MCK * 2;              // 23.66 MB
    _Float16* Bf   = (_Float16*)(ws + off); off += (size_t)NPAD * MCK * 2;             //  0.39 MB

    k_basis2<<<NPAD, 256, 0, stream>>>(Bf);
    k_scan<<<(NLK * LCUT * MCUT) / 256, 256, 0, stream>>>(coeff0, sigma_n, xi, cA);
    k_castA<<<dim3(256, 4), 256, 0, stream>>>(cA, cB);
    k_transP<<<dim3(6, 2, 128), 256, 0, stream>>>(pct, pTf);
    k_leg<<<dim3(6, 128), 256, 0, stream>>>(cB, pTf, xsTh);
    k_castXs<<<dim3(722, 4), 256, 0, stream>>>(xsTh, xsA);
    k_gemm2<<<dim3(361, 6), 256, 0, stream>>>(xsA, Bf, out);
}

// Round 3
// 415.991 us; speedup vs baseline: 1.5221x; 1.0135x over previous
//
#include <hip/hip_runtime.h>
#include <math.h>

// ---- problem constants ----
#define NLATC   361
#define NLONC   722
#define MMAXC   362
#define LMAXC   361
#define NLK     16
#define TSTEPS  8
#define LCUT    128    // sigma_n[l>=128] < 1e-11 -> negligible
#define MCUT    128
#define MCK     256    // 2*MCUT: DFT K-dim
#define TNK     46208  // 8*16*361 rows of the DFT GEMM
#define NPAD    768    // 722 padded to 6*128
#define KPAD    384    // 361 padded to 6*64
#define PHI_F   0.8824969025845955f
#define FOURPI  12.566370614359172f
#define ASCALE  1024.0f       // 2^10: lift coeffs away from fp16 denormals
#define OSCALE  0.0009765625f // 2^-10

typedef _Float16 half8 __attribute__((ext_vector_type(8)));
typedef float floatx4 __attribute__((ext_vector_type(4)));

// ============================================================
// K_PREP: three independent prep jobs, branch by block range.
//   blocks [0,768):       trig basis  -> Bf[j][mc]  fp16
//   blocks [768,2304):    pct transpose -> pTf[m][k(384)][l] fp16
//   blocks [2304,2432):   AR(1) scan -> cB[m][c*128+t*16+n][l] fp16*2^10
// ============================================================
__global__ __launch_bounds__(256) void k_prep(const float* __restrict__ sigma_n,
                                              const float* __restrict__ coeff0,
                                              const float* __restrict__ xi,
                                              const float* __restrict__ pct,
                                              _Float16* __restrict__ Bf,
                                              _Float16* __restrict__ pTf,
                                              _Float16* __restrict__ cB) {
    __shared__ _Float16 sm[64][66];
    int bid = blockIdx.x;
    int tid = threadIdx.x;

    if (bid < 768) {
        // ---- trig basis: Bf[j][mc], j<768 zero-padded ----
        int idx = bid * 256 + tid;
        int j = idx >> 8, mc = idx & 255;
        int m = mc >> 1, c = mc & 1;
        float v = 0.0f;
        if (j < NLONC) {
            int r = (m * j) % NLONC;
            float th = (float)r * (6.283185307179586f / 722.0f);
            float s, co;
            sincosf(th, &s, &co);
            float wq = (m == 0 ? 1.0f : 2.0f) * FOURPI;
            v = c ? (-wq * s) : (wq * co);
        }
        Bf[idx] = (_Float16)v;
    } else if (bid < 2304) {
        // ---- pct[m][l][k] fp32 -> pTf[m][k][l] fp16, m,l<128 ----
        int b = bid - 768;             // 6 * 2 * 128
        int k0 = (b % 6) * 64;
        int l0 = ((b / 6) & 1) * 64;
        int m  = b / 12;
        int tx = tid & 63, ty = tid >> 6;
#pragma unroll
        for (int i = 0; i < 16; ++i) {
            int row = ty * 16 + i;     // l_local
            int k = k0 + tx;
            sm[row][tx] = (k < NLATC)
                ? (_Float16)pct[((size_t)m * LMAXC + l0 + row) * NLATC + k] : (_Float16)0.0f;
        }
        __syncthreads();
#pragma unroll
        for (int i = 0; i < 16; ++i) {
            int kr = ty * 16 + i;      // k_local
            pTf[((size_t)m * KPAD + k0 + kr) * 128 + l0 + tx] = sm[tx][kr];
        }
    } else {
        // ---- AR(1) scan, fused cast/transpose ----
        // block b: mt(4) x lt(2) x n(16); thread: ml(32, fast) x lg(8)
        // thread owns l = lt*64 + lg*8 + [0..7]; writes half8 rows.
        int b = bid - 2304;
        int mt = b & 3, lt = (b >> 2) & 1, n = b >> 3;
        int ml = tid & 31, lg = tid >> 5;
        int m  = mt * 32 + ml;
        int l0 = lt * 64 + lg * 8;
        float cr[8], ci[8], sg[8];
#pragma unroll
        for (int i = 0; i < 8; ++i) {
            int l = l0 + i;
            sg[i] = sigma_n[(size_t)l * MMAXC + m];
            float2 c0 = *(const float2*)&coeff0[(((size_t)n * LMAXC + l) * MMAXC + m) * 2];
            cr[i] = c0.x; ci[i] = c0.y;
        }
#pragma unroll
        for (int t = 0; t < TSTEPS; ++t) {
            half8 hr, hi;
#pragma unroll
            for (int i = 0; i < 8; ++i) {
                hr[i] = (_Float16)(cr[i] * ASCALE);
                hi[i] = (_Float16)(ci[i] * ASCALE);
            }
            size_t rowR = ((size_t)m * 256 +       t * 16 + n) * 128 + l0;
            size_t rowI = ((size_t)m * 256 + 128 + t * 16 + n) * 128 + l0;
            *(half8*)&cB[rowR] = hr;
            *(half8*)&cB[rowI] = hi;
            if (t < TSTEPS - 1) {
#pragma unroll
                for (int i = 0; i < 8; ++i) {
                    float2 x = *(const float2*)
                        &xi[((((size_t)t * NLK + n) * LMAXC + l0 + i) * MMAXC + m) * 2];
                    cr[i] = PHI_F * cr[i] + sg[i] * x.x;
                    ci[i] = PHI_F * ci[i] + sg[i] * x.y;
                }
            }
        }
    }
}

// ============================================================
// K2: Legendre via MFMA, batched over m.
//   C_m[r=(c,t,n); 256][k; 64-tile] = sum_l cB[m][r][l] * pTf[m][k][l]
//   K-loop over l starts at m&~31 (coeff triangular-zero below m).
// ============================================================
__global__ __launch_bounds__(256) void k_leg(const _Float16* __restrict__ cB,
                                             const _Float16* __restrict__ pTf,
                                             _Float16* __restrict__ xsTh) {
    __shared__ _Float16 As[256][40];
    __shared__ _Float16 Bs[64][40];
    int tid = threadIdx.x;
    int k0c = blockIdx.x * 64;
    int m   = blockIdx.y;
    int w = tid >> 6, lane = tid & 63, m16 = lane & 15, quad = lane >> 4;
    floatx4 acc[4][4];
#pragma unroll
    for (int i = 0; i < 4; ++i)
#pragma unroll
        for (int j = 0; j < 4; ++j) acc[i][j] = (floatx4)(0.0f);

    int lt0 = m & ~31;
    for (int lt = lt0; lt < 128; lt += 32) {
#pragma unroll
        for (int it = 0; it < 4; ++it) {
            int r = (tid >> 2) + 64 * it, lc = (tid & 3) * 8;
            *(half8*)&As[r][lc] = *(const half8*)&cB[((size_t)m * 256 + r) * 128 + lt + lc];
        }
        {
            int k = tid >> 2, lc = (tid & 3) * 8;
            *(half8*)&Bs[k][lc] = *(const half8*)&pTf[((size_t)m * KPAD + k0c + k) * 128 + lt + lc];
        }
        __syncthreads();
        half8 a[4], b[4];
#pragma unroll
        for (int i = 0; i < 4; ++i) a[i] = *(const half8*)&As[w * 64 + i * 16 + m16][quad * 8];
#pragma unroll
        for (int j = 0; j < 4; ++j) b[j] = *(const half8*)&Bs[j * 16 + m16][quad * 8];
#pragma unroll
        for (int i = 0; i < 4; ++i)
#pragma unroll
            for (int j = 0; j < 4; ++j)
                acc[i][j] = __builtin_amdgcn_mfma_f32_16x16x32_f16(a[i], b[j], acc[i][j], 0, 0, 0);
        __syncthreads();
    }
#pragma unroll
    for (int i = 0; i < 4; ++i)
#pragma unroll
        for (int j = 0; j < 4; ++j)
#pragma unroll
            for (int reg = 0; reg < 4; ++reg) {
                int r = w * 64 + i * 16 + quad * 4 + reg;
                int c = r >> 7, tn = r & 127;
                int k = k0c + j * 16 + m16;
                if (k < NLATC)
                    xsTh[(size_t)(2 * m + c) * TNK + tn * NLATC + k] = (_Float16)acc[i][j][reg];
            }
}

// ============================================================
// K2b: xsTh fp16 [mc][tnk] -> xsA fp16 [tnk][mc] (64x64 tile transpose)
// ============================================================
__global__ __launch_bounds__(256) void k_castXs(const _Float16* __restrict__ xsTh,
                                                _Float16* __restrict__ xsA) {
    __shared__ _Float16 sm[64][66];
    int tx = threadIdx.x & 63, ty = threadIdx.x >> 6;
    int t0  = blockIdx.x * 64;
    int mc0 = blockIdx.y * 64;
#pragma unroll
    for (int i = 0; i < 16; ++i) {
        int row = ty * 16 + i;         // mc_local
        sm[row][tx] = xsTh[(size_t)(mc0 + row) * TNK + t0 + tx];
    }
    __syncthreads();
#pragma unroll
    for (int i = 0; i < 16; ++i) {
        int row = ty * 16 + i;         // tnk_local
        xsA[(size_t)(t0 + row) * MCK + mc0 + tx] = sm[tx][row];
    }
}

// ============================================================
// K3: DFT via MFMA.  C(46208x722) = xsA(46208x256) * Bf^T ; Bf is [j][mc].
//   128x128 tile, 2x2 waves, 4x4 MFMA tiles each, BK=32, K=256.
// ============================================================
__global__ __launch_bounds__(256) void k_gemm2(const _Float16* __restrict__ A,
                                               const _Float16* __restrict__ Bf,
                                               float* __restrict__ C) {
    __shared__ _Float16 As[128][40];
    __shared__ _Float16 Bs[128][40];
    int tid = threadIdx.x;
    int row0 = blockIdx.x * 128;
    int j0   = blockIdx.y * 128;
    int w = tid >> 6, lane = tid & 63, m16 = lane & 15, quad = lane >> 4;
    int wr = (w & 1) * 64, wc = (w >> 1) * 64;
    floatx4 acc[4][4];
#pragma unroll
    for (int i = 0; i < 4; ++i)
#pragma unroll
        for (int j = 0; j < 4; ++j) acc[i][j] = (floatx4)(0.0f);

    for (int k0 = 0; k0 < MCK; k0 += 32) {
#pragma unroll
        for (int it = 0; it < 2; ++it) {
            int r = (tid >> 2) + 64 * it, kc = (tid & 3) * 8;
            *(half8*)&As[r][kc] = *(const half8*)&A[(size_t)(row0 + r) * MCK + k0 + kc];
            *(half8*)&Bs[r][kc] = *(const half8*)&Bf[(size_t)(j0 + r) * MCK + k0 + kc];
        }
        __syncthreads();
        half8 a[4], b[4];
#pragma unroll
        for (int i = 0; i < 4; ++i) a[i] = *(const half8*)&As[wr + i * 16 + m16][quad * 8];
#pragma unroll
        for (int j = 0; j < 4; ++j) b[j] = *(const half8*)&Bs[wc + j * 16 + m16][quad * 8];
#pragma unroll
        for (int i = 0; i < 4; ++i)
#pragma unroll
            for (int j = 0; j < 4; ++j)
                acc[i][j] = __builtin_amdgcn_mfma_f32_16x16x32_f16(a[i], b[j], acc[i][j], 0, 0, 0);
        __syncthreads();
    }
#pragma unroll
    for (int i = 0; i < 4; ++i)
#pragma unroll
        for (int j = 0; j < 4; ++j)
#pragma unroll
            for (int reg = 0; reg < 4; ++reg) {
                int row = row0 + wr + i * 16 + quad * 4 + reg;
                int col = j0 + wc + j * 16 + m16;
                if (col < NLONC)
                    C[(size_t)row * NLONC + col] = acc[i][j][reg] * OSCALE;
            }
}

extern "C" void kernel_launch(void* const* d_in, const int* in_sizes, int n_in,
                              void* d_out, int out_size, void* d_ws, size_t ws_size,
                              hipStream_t stream) {
    (void)in_sizes; (void)n_in; (void)out_size; (void)ws_size;
    const float* sigma_n = (const float*)d_in[1];
    const float* coeff0  = (const float*)d_in[2];
    const float* xi      = (const float*)d_in[3];
    const float* pct     = (const float*)d_in[4];
    float* out = (float*)d_out;

    char* ws = (char*)d_ws;
    size_t off = 0;
    _Float16* cB   = (_Float16*)(ws + off); off += (size_t)128 * 256 * 128 * 2;   //  8.39 MB
    _Float16* pTf  = (_Float16*)(ws + off); off += (size_t)128 * KPAD * 128 * 2;  // 12.58 MB
    _Float16* xsTh = (_Float16*)(ws + off); off += (size_t)MCK * TNK * 2;         // 23.66 MB
    _Float16* xsA  = (_Float16*)(ws + off); off += (size_t)TNK * MCK * 2;         // 23.66 MB
    _Float16* Bf   = (_Float16*)(ws + off); off += (size_t)NPAD * MCK * 2;        //  0.39 MB

    k_prep<<<2432, 256, 0, stream>>>(sigma_n, coeff0, xi, pct, Bf, pTf, cB);
    k_leg<<<dim3(6, 128), 256, 0, stream>>>(cB, pTf, xsTh);
    k_castXs<<<dim3(722, 4), 256, 0, stream>>>(xsTh, xsA);
    k_gemm2<<<dim3(361, 6), 256, 0, stream>>>(xsA, Bf, out);
}